// Round 8
// baseline (224.358 us; speedup 1.0000x reference)
//
#include <hip/hip_runtime.h>
#include <hip/hip_bf16.h>
#include <cstdint>
#include <cstddef>

// Problem constants (from setup_inputs): B=16, P=768, S=36, Cin=64, C=72
#define BB   16
#define PP   768
#define SS   36
#define CIN  64
#define CC   72
#define NPTS (BB*PP*SS)          // 442368 query points
#define H0 80
#define W0 200
#define H1 40
#define W1 100
#define H2 20
#define W2_ 50

typedef float v4f    __attribute__((ext_vector_type(4)));   // native vec (nontemporal, mfma acc)
typedef short short8 __attribute__((ext_vector_type(8)));   // 8 bf16 = 4 VGPR (mfma A/B frag)

static __device__ __forceinline__ unsigned short f2bf(float x) {
    // round-to-nearest-even f32 -> bf16 (no NaNs in this problem)
    unsigned u = __float_as_uint(x);
    u += 0x7fffu + ((u >> 16) & 1u);
    return (unsigned short)(u >> 16);
}
static __device__ __forceinline__ float bf2f(unsigned u16) {
    return __uint_as_float(u16 << 16);
}
static __device__ __forceinline__ void ld_pair(const unsigned short* p, float& a, float& b) {
    unsigned u = *(const unsigned*)p;           // two adjacent bf16 channels
    a = __uint_as_float((u & 0xffffu) << 16);
    b = __uint_as_float((u >> 16) << 16);
}

// ---------------------------------------------------------------------------
// K1: fold the linear layers into one bf16 A-matrix + one f32 bias vector.
//   Wab rows 0..71  : W2  = weight @ adjust_w      (g-field projection)
//   Wab rows 72..143: ow2 = offset_w @ adjust_w    (offset-field projection)
//   bias144[0..71]  = weight @ adjust_b + bias;  [72..143] = offset_w @ adjust_b + offset_b
// ---------------------------------------------------------------------------
__global__ void prep_mats(const float* __restrict__ adjust_w, const float* __restrict__ adjust_b,
                          const float* __restrict__ offset_w, const float* __restrict__ offset_b,
                          const float* __restrict__ weight,   const float* __restrict__ bias,
                          unsigned short* __restrict__ Wab, float* __restrict__ bias144) {
    int idx = blockIdx.x * 256 + threadIdx.x;
    if (idx < 4608) {
        int o = idx >> 6, k = idx & 63;
        float acc = 0.f;
        for (int c = 0; c < CC; ++c) acc += weight[o*CC + c] * adjust_w[c*CIN + k];
        Wab[o*64 + k] = f2bf(acc);
    } else if (idx < 9216) {
        int j = idx - 4608; int o = j >> 6, k = j & 63;
        float acc = 0.f;
        for (int c = 0; c < CC; ++c) acc += offset_w[o*CC + c] * adjust_w[c*CIN + k];
        Wab[(72 + o)*64 + k] = f2bf(acc);
    } else if (idx < 9288) {
        int o = idx - 9216;
        float acc = bias[o];
        for (int c = 0; c < CC; ++c) acc += weight[o*CC + c] * adjust_b[c];
        bias144[o] = acc;
    } else if (idx < 9360) {
        int o = idx - 9288;
        float acc = offset_b[o];
        for (int c = 0; c < CC; ++c) acc += offset_w[o*CC + c] * adjust_b[c];
        bias144[72 + o] = acc;
    }
}

// ---------------------------------------------------------------------------
// K2 (MFMA): g[px][ch] = Wab[ch][:] . f[:][px] + bias  via mfma_f32_16x16x32_bf16.
// Block = 64 flat pixels, 4 waves x 16 px each. f tile staged in LDS as
// [64 px][64 k] bf16 with (px&7)<<4 XOR swizzle (write 8-way cheap, b128 read
// 2-way free). A-frag from Wab (L2-hot 18KB); C/D: col=px=l&15,
// row=ch=(l>>4)*4+r; bias pre-seeded as C-in. MTILES=9 -> 144 rows (g+off),
// MTILES=5 -> 72 (+8 dead). All three levels dispatched in ONE launch.
// ---------------------------------------------------------------------------
template<int HW, int MTILES, bool WITH_OFF>
static __device__ __forceinline__ void fields_body(
        unsigned bid, const float* __restrict__ f,
        const unsigned short* __restrict__ Wab, const float* __restrict__ bias144,
        unsigned short* __restrict__ g_dst, unsigned short* __restrict__ off_dst,
        char* lds) {
    const int t = threadIdx.x;
    // ---- stage: 4 k-quads per thread, coalesced global read, swizzled LDS write
    {
        const int pxl = t & 63;
        const int q   = t >> 6;                  // 0..3
        const int pxg = (int)bid * 64 + pxl;
        const int b   = pxg / HW;
        const int rem = pxg - b * HW;
        const float* fb = f + (size_t)b * 64 * HW + rem;
        const unsigned swz = (pxl & 7) << 4;
        #pragma unroll
        for (int j = 0; j < 4; ++j) {
            const int k = j * 16 + q * 4;
            float v0 = fb[(size_t)(k + 0) * HW];
            float v1 = fb[(size_t)(k + 1) * HW];
            float v2 = fb[(size_t)(k + 2) * HW];
            float v3 = fb[(size_t)(k + 3) * HW];
            ushort4 pk;
            pk.x = f2bf(v0); pk.y = f2bf(v1); pk.z = f2bf(v2); pk.w = f2bf(v3);
            *(ushort4*)(lds + pxl * 128 + ((unsigned)(j * 32 + q * 8) ^ swz)) = pk;
        }
    }
    __syncthreads();

    // ---- compute: wave w owns px tile [w*16, w*16+16)
    const int ln  = t & 63;
    const int pxw = ((t >> 6) << 4) + (ln & 15);          // local px (B/D column)
    const int kg  = ln >> 4;                              // k-group 0..3
    const unsigned swzr = (pxw & 7) << 4;
    const short8 bf0 = *(const short8*)(lds + pxw * 128 + ((unsigned)(kg * 16)      ^ swzr));
    const short8 bf1 = *(const short8*)(lds + pxw * 128 + ((unsigned)(64 + kg * 16) ^ swzr));

    const int arow = ln & 15;                             // A row within ch tile
    const size_t gbase = ((size_t)bid * 64 + pxw) * (size_t)CC;

    #pragma unroll
    for (int mt = 0; mt < MTILES; ++mt) {
        const int ch0 = mt * 16 + (kg << 2);              // D rows (l>>4)*4 + r
        v4f acc = *(const v4f*)(bias144 + ch0);           // bias pre-seeded as C
        const short8 a0 = *(const short8*)(Wab + (mt * 16 + arow) * 64 + kg * 8);
        const short8 a1 = *(const short8*)(Wab + (mt * 16 + arow) * 64 + 32 + kg * 8);
        acc = __builtin_amdgcn_mfma_f32_16x16x32_bf16(a0, bf0, acc, 0, 0, 0);
        acc = __builtin_amdgcn_mfma_f32_16x16x32_bf16(a1, bf1, acc, 0, 0, 0);
        ushort4 pk;
        pk.x = f2bf(acc[0]); pk.y = f2bf(acc[1]); pk.z = f2bf(acc[2]); pk.w = f2bf(acc[3]);
        if (ch0 < 72) {
            *(ushort4*)(g_dst + gbase + ch0) = pk;
        } else if (WITH_OFF) {
            *(ushort4*)(off_dst + gbase + (ch0 - 72)) = pk;
        }
    }
}

__global__ __launch_bounds__(256) void fields_all(
        const float* __restrict__ f0, const float* __restrict__ f1, const float* __restrict__ f2,
        const unsigned short* __restrict__ Wab, const float* __restrict__ bias144,
        unsigned short* __restrict__ g0, unsigned short* __restrict__ g1,
        unsigned short* __restrict__ g2, unsigned short* __restrict__ offf) {
    __shared__ char lds[64 * 128];               // 8 KB
    const unsigned bid = blockIdx.x;
    if (bid < 4000u) {
        fields_body<16000, 9, true >(bid,         f0, Wab, bias144, g0, offf, lds);
    } else if (bid < 5000u) {
        fields_body< 4000, 5, false>(bid - 4000u, f1, Wab, bias144, g1, nullptr, lds);
    } else {
        fields_body< 1000, 5, false>(bid - 5000u, f2, Wab, bias144, g2, nullptr, lds);
    }
}

// ---------------------------------------------------------------------------
// K3: per query point, bilerp channels (2s, 2s+1) of the offset field and pack
// a 16B point record {gx, gy, dy, dx} so sample does a single dependent load.
// XCD-chunked swizzle: 1728 blocks, 216 per XCD => L2-resident gathers.
// grid read nontemporal (read-once stream, don't evict field lines).
// ---------------------------------------------------------------------------
__global__ __launch_bounds__(256) void dydx_kernel(const float* __restrict__ grid,
                                                   const unsigned short* __restrict__ off_field,
                                                   v4f* __restrict__ pdata) {
    unsigned bid = blockIdx.x;
    bid = (bid & 7u) * (1728u / 8u) + (bid >> 3);        // bijective: 1728 % 8 == 0
    int idx = (int)(bid * 256 + threadIdx.x);            // exact: 1728*256 == NPTS
    int s = idx % SS;
    int b = idx / (PP * SS);
    float gx = __builtin_nontemporal_load(&grid[2 * idx]);
    float gy = __builtin_nontemporal_load(&grid[2 * idx + 1]);
    float ox = (gx + 1.f) * 0.5f * (W0 - 1);
    float oy = (gy + 1.f) * 0.5f * (H0 - 1);
    ox = fminf(fmaxf(ox, 0.f), (float)(W0 - 1));
    oy = fminf(fmaxf(oy, 0.f), (float)(H0 - 1));
    float x0f = floorf(ox), y0f = floorf(oy);
    float wx = ox - x0f, wy = oy - y0f;
    int x0 = (int)x0f, y0 = (int)y0f;
    int x1 = min(x0 + 1, W0 - 1), y1 = min(y0 + 1, H0 - 1);
    size_t base = (size_t)b * H0 * W0;
    int ch = 2 * s;
    float a00, b00, a01, b01, a10, b10, a11, b11;
    ld_pair(off_field + (base + (size_t)y0 * W0 + x0) * CC + ch, a00, b00);
    ld_pair(off_field + (base + (size_t)y0 * W0 + x1) * CC + ch, a01, b01);
    ld_pair(off_field + (base + (size_t)y1 * W0 + x0) * CC + ch, a10, b10);
    ld_pair(off_field + (base + (size_t)y1 * W0 + x1) * CC + ch, a11, b11);
    float top_a = a00 * (1.f - wx) + a01 * wx, bot_a = a10 * (1.f - wx) + a11 * wx;
    float top_b = b00 * (1.f - wx) + b01 * wx, bot_b = b10 * (1.f - wx) + b11 * wx;
    v4f pd;
    pd.x = gx;
    pd.y = gy;
    pd.z = top_a * (1.f - wy) + bot_a * wy;   // dy (channel 2s)
    pd.w = top_b * (1.f - wy) + bot_b * wy;   // dx (channel 2s+1)
    pdata[idx] = pd;
}

// ---------------------------------------------------------------------------
// K4: final sample, dual-item software pipeline. Thread handles items tid and
// tid+256 (same b-region): decode both -> both pdata loads -> all 8 tap loads
// in flight -> compute+store both. 32-bit index math (NPTS*27 < 2^32).
// XCD-chunked swizzle (23328 % 8 == 0); NT stores keep the 382 MB stream out
// of L2 (R7 isolation: removing them costs +43 us); pdata read nontemporal.
// ---------------------------------------------------------------------------
struct SampleItem {
    unsigned q;                 // flat (b,l,p,s)
    int c0;                     // channel group * 8
    const unsigned short* g;    // level base
    int Hl, Wl;
    size_t base;                // b*Hl*Wl
    int pid;
};

static __device__ __forceinline__ SampleItem decode_item(
        unsigned tid, const unsigned short* g0, const unsigned short* g1,
        const unsigned short* g2) {
    SampleItem it;
    unsigned cg = tid % 9u;
    it.q  = tid / 9u;
    it.c0 = (int)cg * 8;
    unsigned s  = it.q % SS;   unsigned q2 = it.q / SS;
    unsigned p  = q2 % PP;     unsigned q3 = q2 / PP;
    unsigned l  = q3 % 3u;     unsigned b  = q3 / 3u;
    it.pid = (int)((b * PP + p) * SS + s);
    if (l == 0u)      { it.Hl = H0; it.Wl = W0;  it.g = g0; }
    else if (l == 1u) { it.Hl = H1; it.Wl = W1;  it.g = g1; }
    else              { it.Hl = H2; it.Wl = W2_; it.g = g2; }
    it.base = (size_t)b * it.Hl * it.Wl;
    return it;
}

static __device__ __forceinline__ void tap_addrs(
        const SampleItem& it, const v4f& pd,
        const unsigned short*& p00, const unsigned short*& p01,
        const unsigned short*& p10, const unsigned short*& p11,
        float& wx, float& wy) {
    float px = (pd.x + 1.f) * 0.5f * (it.Wl - 1) + pd.w;
    float py = (pd.y + 1.f) * 0.5f * (it.Hl - 1) + pd.z;
    px = fminf(fmaxf(px, 0.f), (float)(it.Wl - 1));
    py = fminf(fmaxf(py, 0.f), (float)(it.Hl - 1));
    float x0f = floorf(px), y0f = floorf(py);
    wx = px - x0f; wy = py - y0f;
    int x0 = (int)x0f, y0 = (int)y0f;
    int x1 = min(x0 + 1, it.Wl - 1), y1 = min(y0 + 1, it.Hl - 1);
    p00 = it.g + (it.base + (size_t)y0 * it.Wl + x0) * CC + it.c0;
    p01 = it.g + (it.base + (size_t)y0 * it.Wl + x1) * CC + it.c0;
    p10 = it.g + (it.base + (size_t)y1 * it.Wl + x0) * CC + it.c0;
    p11 = it.g + (it.base + (size_t)y1 * it.Wl + x1) * CC + it.c0;
}

static __device__ __forceinline__ void bilerp_store(
        const uint4& u00, const uint4& u01, const uint4& u10, const uint4& u11,
        float wx, float wy, unsigned q, int c0, float* __restrict__ out) {
    float w00 = (1.f - wx) * (1.f - wy), w01 = wx * (1.f - wy);
    float w10 = (1.f - wx) * wy,         w11 = wx * wy;
    const unsigned* a  = (const unsigned*)&u00;
    const unsigned* bw = (const unsigned*)&u01;
    const unsigned* cw = (const unsigned*)&u10;
    const unsigned* dw = (const unsigned*)&u11;
    float o[8];
    #pragma unroll
    for (int j = 0; j < 4; ++j) {
        float a0  = bf2f(a[j] & 0xffffu),  a1  = bf2f(a[j] >> 16);
        float b0  = bf2f(bw[j] & 0xffffu), b1  = bf2f(bw[j] >> 16);
        float c0v = bf2f(cw[j] & 0xffffu), c1v = bf2f(cw[j] >> 16);
        float d0  = bf2f(dw[j] & 0xffffu), d1  = bf2f(dw[j] >> 16);
        o[2 * j]     = w00 * a0 + w01 * b0 + w10 * c0v + w11 * d0;
        o[2 * j + 1] = w00 * a1 + w01 * b1 + w10 * c1v + w11 * d1;
    }
    size_t ob = (size_t)q * CC + c0;
    v4f r0 = {o[0], o[1], o[2], o[3]};
    v4f r1 = {o[4], o[5], o[6], o[7]};
    __builtin_nontemporal_store(r0, (v4f*)&out[ob]);
    __builtin_nontemporal_store(r1, (v4f*)&out[ob + 4]);
}

__global__ __launch_bounds__(256) void sample_kernel(
        const v4f* __restrict__ pdata,
        const unsigned short* __restrict__ g0, const unsigned short* __restrict__ g1,
        const unsigned short* __restrict__ g2, float* __restrict__ out) {
    unsigned bid = blockIdx.x;
    bid = (bid & 7u) * (23328u / 8u) + (bid >> 3);       // bijective
    const unsigned tidA = bid * 512u + threadIdx.x;      // item A
    const unsigned tidB = tidA + 256u;                   // item B

    SampleItem ia = decode_item(tidA, g0, g1, g2);
    SampleItem ib = decode_item(tidB, g0, g1, g2);

    v4f pdA = __builtin_nontemporal_load(&pdata[ia.pid]);   // both pdata loads issue
    v4f pdB = __builtin_nontemporal_load(&pdata[ib.pid]);

    const unsigned short *a00, *a01, *a10, *a11, *b00, *b01, *b10, *b11;
    float wxA, wyA, wxB, wyB;
    tap_addrs(ia, pdA, a00, a01, a10, a11, wxA, wyA);
    tap_addrs(ib, pdB, b00, b01, b10, b11, wxB, wyB);

    // all 8 tap loads in flight before any use
    uint4 uA00 = *(const uint4*)a00;
    uint4 uA01 = *(const uint4*)a01;
    uint4 uA10 = *(const uint4*)a10;
    uint4 uA11 = *(const uint4*)a11;
    uint4 uB00 = *(const uint4*)b00;
    uint4 uB01 = *(const uint4*)b01;
    uint4 uB10 = *(const uint4*)b10;
    uint4 uB11 = *(const uint4*)b11;

    bilerp_store(uA00, uA01, uA10, uA11, wxA, wyA, ia.q, ia.c0, out);
    bilerp_store(uB00, uB01, uB10, uB11, wxB, wyB, ib.q, ib.c0, out);
}

// ---------------------------------------------------------------------------
extern "C" void kernel_launch(void* const* d_in, const int* in_sizes, int n_in,
                              void* d_out, int out_size, void* d_ws, size_t ws_size,
                              hipStream_t stream) {
    const float* f0       = (const float*)d_in[0];
    const float* f1       = (const float*)d_in[1];
    const float* f2       = (const float*)d_in[2];
    const float* grid     = (const float*)d_in[3];
    const float* adjust_w = (const float*)d_in[4];
    const float* adjust_b = (const float*)d_in[5];
    const float* offset_w = (const float*)d_in[6];
    const float* offset_b = (const float*)d_in[7];
    const float* weight   = (const float*)d_in[8];
    const float* bias     = (const float*)d_in[9];

    // workspace layout (bytes); total ~53 MB
    char* ws = (char*)d_ws;
    unsigned short* Wab   = (unsigned short*)(ws + 0);        // 144x64 bf16 = 18432 B
    float*          b144  = (float*)(ws + 18432);             // 144 f32
    v4f*            pdata = (v4f*)(ws + 19200);               // NPTS x 16 B = 7077888
    unsigned short* g0    = (unsigned short*)(ws + 7097088);  // 36864000 B
    unsigned short* g1    = (unsigned short*)(ws + 43961088); // 9216000 B
    unsigned short* g2    = (unsigned short*)(ws + 53177088); // 2304000 B -> end 55481088
    // offset field parked in d_out (first ~37 MB), consumed by dydx_kernel
    // before sample_kernel overwrites all of d_out.
    unsigned short* offf = (unsigned short*)d_out;

    prep_mats<<<37, 256, 0, stream>>>(adjust_w, adjust_b, offset_w, offset_b,
                                      weight, bias, Wab, b144);

    fields_all<<<5250, 256, 0, stream>>>(f0, f1, f2, Wab, b144, g0, g1, g2, offf);

    dydx_kernel<<<1728, 256, 0, stream>>>(grid, offf, pdata);

    sample_kernel<<<23328, 256, 0, stream>>>(pdata, g0, g1, g2, (float*)d_out);
}

// Round 9
// 159.942 us; speedup vs baseline: 1.4027x; 1.4027x over previous
//
#include <hip/hip_runtime.h>
#include <hip/hip_bf16.h>
#include <cstdint>
#include <cstddef>

// Problem constants (from setup_inputs): B=16, P=768, S=36, Cin=64, C=72
#define BB   16
#define PP   768
#define SS   36
#define CIN  64
#define CC   72
#define NPTS (BB*PP*SS)          // 442368 query points
#define H0 80
#define W0 200
#define H1 40
#define W1 100
#define H2 20
#define W2_ 50

typedef float v4f    __attribute__((ext_vector_type(4)));   // native vec (nontemporal, mfma acc)
typedef short short8 __attribute__((ext_vector_type(8)));   // 8 bf16 = 4 VGPR (mfma A/B frag)

static __device__ __forceinline__ unsigned short f2bf(float x) {
    // round-to-nearest-even f32 -> bf16 (no NaNs in this problem)
    unsigned u = __float_as_uint(x);
    u += 0x7fffu + ((u >> 16) & 1u);
    return (unsigned short)(u >> 16);
}
static __device__ __forceinline__ float bf2f(unsigned u16) {
    return __uint_as_float(u16 << 16);
}
static __device__ __forceinline__ void ld_pair(const unsigned short* p, float& a, float& b) {
    unsigned u = *(const unsigned*)p;           // two adjacent bf16 channels
    a = __uint_as_float((u & 0xffffu) << 16);
    b = __uint_as_float((u >> 16) << 16);
}

// ---------------------------------------------------------------------------
// K1: fold the linear layers into one bf16 A-matrix + one f32 bias vector.
//   Wab rows 0..71  : W2  = weight @ adjust_w      (g-field projection)
//   Wab rows 72..143: ow2 = offset_w @ adjust_w    (offset-field projection)
//   bias144[0..71]  = weight @ adjust_b + bias;  [72..143] = offset_w @ adjust_b + offset_b
// ---------------------------------------------------------------------------
__global__ void prep_mats(const float* __restrict__ adjust_w, const float* __restrict__ adjust_b,
                          const float* __restrict__ offset_w, const float* __restrict__ offset_b,
                          const float* __restrict__ weight,   const float* __restrict__ bias,
                          unsigned short* __restrict__ Wab, float* __restrict__ bias144) {
    int idx = blockIdx.x * 256 + threadIdx.x;
    if (idx < 4608) {
        int o = idx >> 6, k = idx & 63;
        float acc = 0.f;
        for (int c = 0; c < CC; ++c) acc += weight[o*CC + c] * adjust_w[c*CIN + k];
        Wab[o*64 + k] = f2bf(acc);
    } else if (idx < 9216) {
        int j = idx - 4608; int o = j >> 6, k = j & 63;
        float acc = 0.f;
        for (int c = 0; c < CC; ++c) acc += offset_w[o*CC + c] * adjust_w[c*CIN + k];
        Wab[(72 + o)*64 + k] = f2bf(acc);
    } else if (idx < 9288) {
        int o = idx - 9216;
        float acc = bias[o];
        for (int c = 0; c < CC; ++c) acc += weight[o*CC + c] * adjust_b[c];
        bias144[o] = acc;
    } else if (idx < 9360) {
        int o = idx - 9288;
        float acc = offset_b[o];
        for (int c = 0; c < CC; ++c) acc += offset_w[o*CC + c] * adjust_b[c];
        bias144[72 + o] = acc;
    }
}

// ---------------------------------------------------------------------------
// K2 (MFMA): g[px][ch] = Wab[ch][:] . f[:][px] + bias  via mfma_f32_16x16x32_bf16.
// Block = 64 flat pixels, 4 waves x 16 px each. f tile staged in LDS as
// [64 px][64 k] bf16 with (px&7)<<4 XOR swizzle (write 8-way cheap, b128 read
// 2-way free). A-frag from Wab (L2-hot 18KB); C/D: col=px=l&15,
// row=ch=(l>>4)*4+r; bias pre-seeded as C-in. MTILES=9 -> 144 rows (g+off),
// MTILES=5 -> 72 (+8 dead). All three levels dispatched in ONE launch.
// ---------------------------------------------------------------------------
template<int HW, int MTILES, bool WITH_OFF>
static __device__ __forceinline__ void fields_body(
        unsigned bid, const float* __restrict__ f,
        const unsigned short* __restrict__ Wab, const float* __restrict__ bias144,
        unsigned short* __restrict__ g_dst, unsigned short* __restrict__ off_dst,
        char* lds) {
    const int t = threadIdx.x;
    // ---- stage: 4 k-quads per thread, coalesced global read, swizzled LDS write
    {
        const int pxl = t & 63;
        const int q   = t >> 6;                  // 0..3
        const int pxg = (int)bid * 64 + pxl;
        const int b   = pxg / HW;
        const int rem = pxg - b * HW;
        const float* fb = f + (size_t)b * 64 * HW + rem;
        const unsigned swz = (pxl & 7) << 4;
        #pragma unroll
        for (int j = 0; j < 4; ++j) {
            const int k = j * 16 + q * 4;
            float v0 = fb[(size_t)(k + 0) * HW];
            float v1 = fb[(size_t)(k + 1) * HW];
            float v2 = fb[(size_t)(k + 2) * HW];
            float v3 = fb[(size_t)(k + 3) * HW];
            ushort4 pk;
            pk.x = f2bf(v0); pk.y = f2bf(v1); pk.z = f2bf(v2); pk.w = f2bf(v3);
            *(ushort4*)(lds + pxl * 128 + ((unsigned)(j * 32 + q * 8) ^ swz)) = pk;
        }
    }
    __syncthreads();

    // ---- compute: wave w owns px tile [w*16, w*16+16)
    const int ln  = t & 63;
    const int pxw = ((t >> 6) << 4) + (ln & 15);          // local px (B/D column)
    const int kg  = ln >> 4;                              // k-group 0..3
    const unsigned swzr = (pxw & 7) << 4;
    const short8 bf0 = *(const short8*)(lds + pxw * 128 + ((unsigned)(kg * 16)      ^ swzr));
    const short8 bf1 = *(const short8*)(lds + pxw * 128 + ((unsigned)(64 + kg * 16) ^ swzr));

    const int arow = ln & 15;                             // A row within ch tile
    const size_t gbase = ((size_t)bid * 64 + pxw) * (size_t)CC;

    #pragma unroll
    for (int mt = 0; mt < MTILES; ++mt) {
        const int ch0 = mt * 16 + (kg << 2);              // D rows (l>>4)*4 + r
        v4f acc = *(const v4f*)(bias144 + ch0);           // bias pre-seeded as C
        const short8 a0 = *(const short8*)(Wab + (mt * 16 + arow) * 64 + kg * 8);
        const short8 a1 = *(const short8*)(Wab + (mt * 16 + arow) * 64 + 32 + kg * 8);
        acc = __builtin_amdgcn_mfma_f32_16x16x32_bf16(a0, bf0, acc, 0, 0, 0);
        acc = __builtin_amdgcn_mfma_f32_16x16x32_bf16(a1, bf1, acc, 0, 0, 0);
        ushort4 pk;
        pk.x = f2bf(acc[0]); pk.y = f2bf(acc[1]); pk.z = f2bf(acc[2]); pk.w = f2bf(acc[3]);
        if (ch0 < 72) {
            *(ushort4*)(g_dst + gbase + ch0) = pk;
        } else if (WITH_OFF) {
            *(ushort4*)(off_dst + gbase + (ch0 - 72)) = pk;
        }
    }
}

__global__ __launch_bounds__(256) void fields_all(
        const float* __restrict__ f0, const float* __restrict__ f1, const float* __restrict__ f2,
        const unsigned short* __restrict__ Wab, const float* __restrict__ bias144,
        unsigned short* __restrict__ g0, unsigned short* __restrict__ g1,
        unsigned short* __restrict__ g2, unsigned short* __restrict__ offf) {
    __shared__ char lds[64 * 128];               // 8 KB
    const unsigned bid = blockIdx.x;
    if (bid < 4000u) {
        fields_body<16000, 9, true >(bid,         f0, Wab, bias144, g0, offf, lds);
    } else if (bid < 5000u) {
        fields_body< 4000, 5, false>(bid - 4000u, f1, Wab, bias144, g1, nullptr, lds);
    } else {
        fields_body< 1000, 5, false>(bid - 5000u, f2, Wab, bias144, g2, nullptr, lds);
    }
}

// ---------------------------------------------------------------------------
// K3: per query point, bilerp channels (2s, 2s+1) of the offset field and pack
// a 16B point record {gx, gy, dy, dx} so sample does a single dependent load.
// XCD-chunked swizzle: 1728 blocks, 216 per XCD => L2-resident gathers.
// All loads REGULAR (R8 isolation: NT loads on producer-written data cost +64 us).
// ---------------------------------------------------------------------------
__global__ __launch_bounds__(256) void dydx_kernel(const float* __restrict__ grid,
                                                   const unsigned short* __restrict__ off_field,
                                                   v4f* __restrict__ pdata) {
    unsigned bid = blockIdx.x;
    bid = (bid & 7u) * (1728u / 8u) + (bid >> 3);        // bijective: 1728 % 8 == 0
    int idx = (int)(bid * 256 + threadIdx.x);            // exact: 1728*256 == NPTS
    int s = idx % SS;
    int b = idx / (PP * SS);
    float gx = grid[2 * idx], gy = grid[2 * idx + 1];
    float ox = (gx + 1.f) * 0.5f * (W0 - 1);
    float oy = (gy + 1.f) * 0.5f * (H0 - 1);
    ox = fminf(fmaxf(ox, 0.f), (float)(W0 - 1));
    oy = fminf(fmaxf(oy, 0.f), (float)(H0 - 1));
    float x0f = floorf(ox), y0f = floorf(oy);
    float wx = ox - x0f, wy = oy - y0f;
    int x0 = (int)x0f, y0 = (int)y0f;
    int x1 = min(x0 + 1, W0 - 1), y1 = min(y0 + 1, H0 - 1);
    size_t base = (size_t)b * H0 * W0;
    int ch = 2 * s;
    float a00, b00, a01, b01, a10, b10, a11, b11;
    ld_pair(off_field + (base + (size_t)y0 * W0 + x0) * CC + ch, a00, b00);
    ld_pair(off_field + (base + (size_t)y0 * W0 + x1) * CC + ch, a01, b01);
    ld_pair(off_field + (base + (size_t)y1 * W0 + x0) * CC + ch, a10, b10);
    ld_pair(off_field + (base + (size_t)y1 * W0 + x1) * CC + ch, a11, b11);
    float top_a = a00 * (1.f - wx) + a01 * wx, bot_a = a10 * (1.f - wx) + a11 * wx;
    float top_b = b00 * (1.f - wx) + b01 * wx, bot_b = b10 * (1.f - wx) + b11 * wx;
    v4f pd;
    pd.x = gx;
    pd.y = gy;
    pd.z = top_a * (1.f - wy) + bot_a * wy;   // dy (channel 2s)
    pd.w = top_b * (1.f - wy) + bot_b * wy;   // dx (channel 2s+1)
    pdata[idx] = pd;
}

// ---------------------------------------------------------------------------
// K4: final sample, dual-item software pipeline. Thread handles items tid and
// tid+256 (same b-region): decode both -> both pdata loads -> all 8 tap loads
// in flight -> compute+store both. 32-bit index math (NPTS*27 < 2^32).
// XCD-chunked swizzle (23328 % 8 == 0).
// NT stores ONLY (R7: removing them costs +43 us); loads regular (R8: NT
// loads on L2/L3-hot producer data cost +64 us).
// ---------------------------------------------------------------------------
struct SampleItem {
    unsigned q;                 // flat (b,l,p,s)
    int c0;                     // channel group * 8
    const unsigned short* g;    // level base
    int Hl, Wl;
    size_t base;                // b*Hl*Wl
    int pid;
};

static __device__ __forceinline__ SampleItem decode_item(
        unsigned tid, const unsigned short* g0, const unsigned short* g1,
        const unsigned short* g2) {
    SampleItem it;
    unsigned cg = tid % 9u;
    it.q  = tid / 9u;
    it.c0 = (int)cg * 8;
    unsigned s  = it.q % SS;   unsigned q2 = it.q / SS;
    unsigned p  = q2 % PP;     unsigned q3 = q2 / PP;
    unsigned l  = q3 % 3u;     unsigned b  = q3 / 3u;
    it.pid = (int)((b * PP + p) * SS + s);
    if (l == 0u)      { it.Hl = H0; it.Wl = W0;  it.g = g0; }
    else if (l == 1u) { it.Hl = H1; it.Wl = W1;  it.g = g1; }
    else              { it.Hl = H2; it.Wl = W2_; it.g = g2; }
    it.base = (size_t)b * it.Hl * it.Wl;
    return it;
}

static __device__ __forceinline__ void tap_addrs(
        const SampleItem& it, const v4f& pd,
        const unsigned short*& p00, const unsigned short*& p01,
        const unsigned short*& p10, const unsigned short*& p11,
        float& wx, float& wy) {
    float px = (pd.x + 1.f) * 0.5f * (it.Wl - 1) + pd.w;
    float py = (pd.y + 1.f) * 0.5f * (it.Hl - 1) + pd.z;
    px = fminf(fmaxf(px, 0.f), (float)(it.Wl - 1));
    py = fminf(fmaxf(py, 0.f), (float)(it.Hl - 1));
    float x0f = floorf(px), y0f = floorf(py);
    wx = px - x0f; wy = py - y0f;
    int x0 = (int)x0f, y0 = (int)y0f;
    int x1 = min(x0 + 1, it.Wl - 1), y1 = min(y0 + 1, it.Hl - 1);
    p00 = it.g + (it.base + (size_t)y0 * it.Wl + x0) * CC + it.c0;
    p01 = it.g + (it.base + (size_t)y0 * it.Wl + x1) * CC + it.c0;
    p10 = it.g + (it.base + (size_t)y1 * it.Wl + x0) * CC + it.c0;
    p11 = it.g + (it.base + (size_t)y1 * it.Wl + x1) * CC + it.c0;
}

static __device__ __forceinline__ void bilerp_store(
        const uint4& u00, const uint4& u01, const uint4& u10, const uint4& u11,
        float wx, float wy, unsigned q, int c0, float* __restrict__ out) {
    float w00 = (1.f - wx) * (1.f - wy), w01 = wx * (1.f - wy);
    float w10 = (1.f - wx) * wy,         w11 = wx * wy;
    const unsigned* a  = (const unsigned*)&u00;
    const unsigned* bw = (const unsigned*)&u01;
    const unsigned* cw = (const unsigned*)&u10;
    const unsigned* dw = (const unsigned*)&u11;
    float o[8];
    #pragma unroll
    for (int j = 0; j < 4; ++j) {
        float a0  = bf2f(a[j] & 0xffffu),  a1  = bf2f(a[j] >> 16);
        float b0  = bf2f(bw[j] & 0xffffu), b1  = bf2f(bw[j] >> 16);
        float c0v = bf2f(cw[j] & 0xffffu), c1v = bf2f(cw[j] >> 16);
        float d0  = bf2f(dw[j] & 0xffffu), d1  = bf2f(dw[j] >> 16);
        o[2 * j]     = w00 * a0 + w01 * b0 + w10 * c0v + w11 * d0;
        o[2 * j + 1] = w00 * a1 + w01 * b1 + w10 * c1v + w11 * d1;
    }
    size_t ob = (size_t)q * CC + c0;
    v4f r0 = {o[0], o[1], o[2], o[3]};
    v4f r1 = {o[4], o[5], o[6], o[7]};
    __builtin_nontemporal_store(r0, (v4f*)&out[ob]);
    __builtin_nontemporal_store(r1, (v4f*)&out[ob + 4]);
}

__global__ __launch_bounds__(256) void sample_kernel(
        const v4f* __restrict__ pdata,
        const unsigned short* __restrict__ g0, const unsigned short* __restrict__ g1,
        const unsigned short* __restrict__ g2, float* __restrict__ out) {
    unsigned bid = blockIdx.x;
    bid = (bid & 7u) * (23328u / 8u) + (bid >> 3);       // bijective
    const unsigned tidA = bid * 512u + threadIdx.x;      // item A
    const unsigned tidB = tidA + 256u;                   // item B

    SampleItem ia = decode_item(tidA, g0, g1, g2);
    SampleItem ib = decode_item(tidB, g0, g1, g2);

    v4f pdA = pdata[ia.pid];                             // both pdata loads issue
    v4f pdB = pdata[ib.pid];

    const unsigned short *a00, *a01, *a10, *a11, *b00, *b01, *b10, *b11;
    float wxA, wyA, wxB, wyB;
    tap_addrs(ia, pdA, a00, a01, a10, a11, wxA, wyA);
    tap_addrs(ib, pdB, b00, b01, b10, b11, wxB, wyB);

    // all 8 tap loads in flight before any use
    uint4 uA00 = *(const uint4*)a00;
    uint4 uA01 = *(const uint4*)a01;
    uint4 uA10 = *(const uint4*)a10;
    uint4 uA11 = *(const uint4*)a11;
    uint4 uB00 = *(const uint4*)b00;
    uint4 uB01 = *(const uint4*)b01;
    uint4 uB10 = *(const uint4*)b10;
    uint4 uB11 = *(const uint4*)b11;

    bilerp_store(uA00, uA01, uA10, uA11, wxA, wyA, ia.q, ia.c0, out);
    bilerp_store(uB00, uB01, uB10, uB11, wxB, wyB, ib.q, ib.c0, out);
}

// ---------------------------------------------------------------------------
extern "C" void kernel_launch(void* const* d_in, const int* in_sizes, int n_in,
                              void* d_out, int out_size, void* d_ws, size_t ws_size,
                              hipStream_t stream) {
    const float* f0       = (const float*)d_in[0];
    const float* f1       = (const float*)d_in[1];
    const float* f2       = (const float*)d_in[2];
    const float* grid     = (const float*)d_in[3];
    const float* adjust_w = (const float*)d_in[4];
    const float* adjust_b = (const float*)d_in[5];
    const float* offset_w = (const float*)d_in[6];
    const float* offset_b = (const float*)d_in[7];
    const float* weight   = (const float*)d_in[8];
    const float* bias     = (const float*)d_in[9];

    // workspace layout (bytes); total ~53 MB
    char* ws = (char*)d_ws;
    unsigned short* Wab   = (unsigned short*)(ws + 0);        // 144x64 bf16 = 18432 B
    float*          b144  = (float*)(ws + 18432);             // 144 f32
    v4f*            pdata = (v4f*)(ws + 19200);               // NPTS x 16 B = 7077888
    unsigned short* g0    = (unsigned short*)(ws + 7097088);  // 36864000 B
    unsigned short* g1    = (unsigned short*)(ws + 43961088); // 9216000 B
    unsigned short* g2    = (unsigned short*)(ws + 53177088); // 2304000 B -> end 55481088
    // offset field parked in d_out (first ~37 MB), consumed by dydx_kernel
    // before sample_kernel overwrites all of d_out.
    unsigned short* offf = (unsigned short*)d_out;

    prep_mats<<<37, 256, 0, stream>>>(adjust_w, adjust_b, offset_w, offset_b,
                                      weight, bias, Wab, b144);

    fields_all<<<5250, 256, 0, stream>>>(f0, f1, f2, Wab, b144, g0, g1, g2, offf);

    dydx_kernel<<<1728, 256, 0, stream>>>(grid, offf, pdata);

    sample_kernel<<<23328, 256, 0, stream>>>(pdata, g0, g1, g2, (float*)d_out);
}